// Round 2
// baseline (595.088 us; speedup 1.0000x reference)
//
#include <hip/hip_runtime.h>
#include <hip/hip_bf16.h>

// NeighborlistVerletNsq: all-unique-pairs minimum-image displacement + distance
// + verlet-build / cutoff masks on MI355X.
//
// N = 6144 particles, P = N(N-1)/2 = 18,871,296 pairs.
// Output layout (flat f32, concatenated in reference return order):
//   [0,      3P)  r_ij  (row-major [P,3])
//   [3P,     4P)  d_ij
//   [4P,     5P)  in_build  (1.0f / 0.0f)
//   [5P,     6P)  in_cutoff (1.0f / 0.0f)
//
// R2: 4 pairs per thread -> triangular inversion amortized 4x, and ALL stores
// become contiguous float4 (r_ij: 12 consecutive floats = 3x dwordx4; d/masks:
// 1x dwordx4 each). Nontemporal stores: 453 MB streamed write, never re-read.

#define NPART 6144
#define PAIRS 18871296          // N*(N-1)/2, divisible by 4
#define PPT 4                   // pairs per thread

typedef float v4 __attribute__((ext_vector_type(4)));

// Replicates jnp.remainder(t, L) then -half, bitwise in fp32, for the
// restricted domain t in (-L/2, 3L/2) that holds because positions in [0, L):
//   fmod(t,L) = t-L  (t >= L; Sterbenz-exact subtraction)
//             = t    (0 <= t < L)
//             = t    (t < 0), then remainder-adjust adds L in fp32.
__device__ __forceinline__ float min_image(float diff, float L, float half) {
    float t = __fadd_rn(diff, half);
    float m = t;
    if (t >= L)       m = __fsub_rn(t, L);
    else if (t < 0.f) m = __fadd_rn(t, L);
    return __fsub_rn(m, half);
}

__global__ __launch_bounds__(256) void nsq_pairs_kernel(
    const float* __restrict__ pos,   // [N,3]
    const float* __restrict__ box,   // [3,3] diagonal
    float* __restrict__ out)
{
    int t = blockIdx.x * blockDim.x + threadIdx.x;
    int p = t * PPT;                 // first pair of this thread
    if (p >= PAIRS) return;

    // ---- invert p -> (i, j), i < j, np.triu_indices order (once per 4 pairs)
    const double A = (double)(2 * NPART - 1);
    double disc = A * A - 8.0 * (double)p;
    int i = (int)((A - sqrt(disc)) * 0.5);
    i = max(0, min(i, NPART - 2));
    int rs = i * NPART - (i * (i + 1)) / 2;       // row_start(i)
    int rlen = NPART - 1 - i;
    while (p >= rs + rlen) { rs += rlen; ++i; rlen = NPART - 1 - i; }
    while (p < rs)         { rs -= (NPART - i); --i; rlen = NPART - 1 - i; }
    int j = i + 1 + (p - rs);

    // ---- uniform box params (scalar-loaded) ----
    float Lx = box[0], Ly = box[4], Lz = box[8];
    float hx = __fmul_rn(Lx, 0.5f);
    float hy = __fmul_rn(Ly, 0.5f);
    float hz = __fmul_rn(Lz, 0.5f);

    float xi = pos[3 * i + 0], yi = pos[3 * i + 1], zi = pos[3 * i + 2];

    float r[PPT][3], dv[PPT], bm[PPT], cm[PPT];

#pragma unroll
    for (int k = 0; k < PPT; ++k) {
        float xj = pos[3 * j + 0], yj = pos[3 * j + 1], zj = pos[3 * j + 2];

        float rx = min_image(__fsub_rn(xi, xj), Lx, hx);
        float ry = min_image(__fsub_rn(yi, yj), Ly, hy);
        float rz = min_image(__fsub_rn(zi, zj), Lz, hz);

        float s = __fadd_rn(__fadd_rn(__fmul_rn(rx, rx), __fmul_rn(ry, ry)),
                            __fmul_rn(rz, rz));
        float d = sqrtf(s);

        r[k][0] = rx; r[k][1] = ry; r[k][2] = rz;
        dv[k] = d;
        bm[k] = (d <  0.6f) ? 1.0f : 0.0f;   // CUTOFF + SKIN
        cm[k] = (d <= 0.5f) ? 1.0f : 0.0f;   // CUTOFF

        if (k < PPT - 1) {                   // advance to next pair
            ++j;
            if (j >= NPART) {                // row wrap: (i+1, i+2)
                ++i;
                j = i + 1;
                xi = pos[3 * i + 0]; yi = pos[3 * i + 1]; zi = pos[3 * i + 2];
            }
        }
    }

    // ---- all-contiguous float4 nontemporal stores ----
    const int P = PAIRS;
    v4* r_out = (v4*)(out + 3 * p);          // 12 floats, 16B-aligned (p%4==0)
    v4 r0 = { r[0][0], r[0][1], r[0][2], r[1][0] };
    v4 r1 = { r[1][1], r[1][2], r[2][0], r[2][1] };
    v4 r2 = { r[2][2], r[3][0], r[3][1], r[3][2] };
    __builtin_nontemporal_store(r0, r_out + 0);
    __builtin_nontemporal_store(r1, r_out + 1);
    __builtin_nontemporal_store(r2, r_out + 2);

    v4 d4 = { dv[0], dv[1], dv[2], dv[3] };
    v4 b4 = { bm[0], bm[1], bm[2], bm[3] };
    v4 c4 = { cm[0], cm[1], cm[2], cm[3] };
    __builtin_nontemporal_store(d4, (v4*)(out + 3 * P + p));
    __builtin_nontemporal_store(b4, (v4*)(out + 4 * P + p));
    __builtin_nontemporal_store(c4, (v4*)(out + 5 * P + p));
}

extern "C" void kernel_launch(void* const* d_in, const int* in_sizes, int n_in,
                              void* d_out, int out_size, void* d_ws, size_t ws_size,
                              hipStream_t stream) {
    const float* pos = (const float*)d_in[0];   // [6144, 3] f32
    const float* box = (const float*)d_in[1];   // [3, 3]  f32
    float* out = (float*)d_out;                 // 6P f32

    const int block = 256;
    const int threads_total = PAIRS / PPT;      // 4,717,824 (exact multiple)
    const int grid = threads_total / block;     // 18,429 blocks (exact)
    nsq_pairs_kernel<<<grid, block, 0, stream>>>(pos, box, out);
}